// Round 2
// baseline (419.934 us; speedup 1.0000x reference)
//
#include <hip/hip_runtime.h>

#define EPS 5e-4f
#define LOG2E 1.4426950408889634f
#define BATCH 32
#define N 2048
#define NT 32   // 64-wide tiles per row
#define QW 16   // pair-kernel blocks per row (u = 0..15 pairs tilerows u and 31-u)

__device__ __forceinline__ float fexp2(float x) { return __builtin_amdgcn_exp2f(x); }
__device__ __forceinline__ float frcp(float x)  { return __builtin_amdgcn_rcpf(x); }

// Kernel 1: pairwise sigmoid sums S_k = sum_{l != k} sigmoid(p_l - p_k), using
// the symmetry sigma(x)+sigma(-x)=1 so each exp2+rcp serves TWO directed pairs.
// Block = (row r, u): handles tilerows u and 31-u of the upper-triangle tile
// grid (33 tiles, balanced). Row sums accumulate in registers; the symmetric
// (column) contributions go into a doubled LDS accumulator via ds_add_f32 so
// every address is base + lane*4 + const (no per-iter address math, 2-way bank
// aliasing = free). Each block writes its partial S to a private ws slice.
__global__ __launch_bounds__(256) void pairs_kernel(const float* __restrict__ y_pred,
                                                    float* __restrict__ ws) {
    const int r    = blockIdx.y;
    const int u    = blockIdx.x;          // 0..15
    const int v    = 31 - u;
    const int tid  = threadIdx.x;
    const int lane = tid & 63;
    const int wave = tid >> 6;

    __shared__ float pdL[NT * 128];   // row, pre-scaled by LOG2E, each tile doubled
    __shared__ float scol[NT * 128];  // doubled column accumulator

    const float* yp = y_pred + r * N;
    for (int e = tid; e < NT * 128; e += 256) {
        int t = e >> 7, c = e & 127;
        pdL[e]  = yp[t * 64 + (c & 63)] * LOG2E;
        scol[e] = 0.f;
    }
    __syncthreads();

    const int nu = 32 - u;                // tiles in tilerow u (j = u..31)
    for (int idx = wave; idx < 33; idx += 4) {
        int i, j;
        if (idx < nu) { i = u; j = u + idx; }
        else          { i = v; j = v + (idx - nu); }

        const float aL = pdL[i * 128 + lane];
        const float* pb = &pdL[j * 128 + lane];
        float* sc = &scol[j * 128 + lane];
        float accA = 0.f;

        if (i != j) {
            // off-diagonal tile: all 64 rotations, both directions per pair
#pragma unroll
            for (int jj = 0; jj < 64; ++jj) {
                float bL = pb[jj];
                float uu = fexp2(aL - bL);          // 2^{(pa-pb)·log2e}
                float rr = frcp(1.f + uu);          // sigma(pb - pa) -> row a
                accA += rr;
                atomicAdd(&sc[jj], 1.f - rr);       // sigma(pa - pb) -> row b
            }
        } else {
            // diagonal tile: rotations 0..31 with symmetric credit cover gaps
            // 1..31 both directions (jj=0 adds a spurious self term 0.5+0.5,
            // removed below); jj=32 covers the gap-32 pairs as ordered pairs.
#pragma unroll
            for (int jj = 0; jj < 32; ++jj) {
                float bL = pb[jj];
                float uu = fexp2(aL - bL);
                float rr = frcp(1.f + uu);
                accA += rr;
                atomicAdd(&sc[jj], 1.f - rr);
            }
            {
                float bL = pb[32];
                float uu = fexp2(aL - bL);
                float rr = frcp(1.f + uu);
                accA += rr;
            }
            accA -= 1.0f;   // cancel the jj=0 self contribution (0.5 here + 0.5 col)
        }
        atomicAdd(&scol[i * 128 + lane], accA);     // flush row sums for this tile
    }
    __syncthreads();

    // fold the doubled copies and write this block's private partial-S slice
    float* wsl = ws + ((size_t)r * QW + u) * N;
    for (int c = tid; c < N; c += 256) {
        int t = c >> 6, m = c & 63;
        wsl[c] = scol[t * 128 + m] + scol[t * 128 + 64 + m];
    }
}

// Kernel 2 (one block per row): maxDCG via 5-bin histogram (labels are ints
// 0..4, so descending sort == rank ranges), then the finalize sweep:
// sum_k (2^{t_k}-1)/maxDCG / log2(2 + S_k), block-reduce, atomic into out.
__global__ __launch_bounds__(256) void finalize_kernel(const float* __restrict__ y_true,
                                                       const float* __restrict__ ws,
                                                       float* __restrict__ out) {
    const int r   = blockIdx.x;
    const int tid = threadIdx.x;
    __shared__ int cnt[5];
    __shared__ float red[256];
    __shared__ float inv_maxdcg;
    if (tid < 5) cnt[tid] = 0;
    __syncthreads();

    const float* yt = y_true + r * N;
    int c1 = 0, c2 = 0, c3 = 0, c4 = 0;
    for (int i = tid; i < N; i += 256) {
        int vv = (int)yt[i];
        c1 += (vv == 1); c2 += (vv == 2); c3 += (vv == 3); c4 += (vv == 4);
    }
    atomicAdd(&cnt[1], c1);
    atomicAdd(&cnt[2], c2);
    atomicAdd(&cnt[3], c3);
    atomicAdd(&cnt[4], c4);
    __syncthreads();

    const int cum4 = cnt[4];
    const int cum3 = cum4 + cnt[3];
    const int cum2 = cum3 + cnt[2];
    const int cum1 = cum2 + cnt[1];

    float part = 0.f;
    for (int rr = tid + 1; rr <= N; rr += 256) {
        float g = (rr <= cum4) ? 15.f : (rr <= cum3) ? 7.f
                : (rr <= cum2) ? 3.f  : (rr <= cum1) ? 1.f : 0.f;
        if (g > 0.f) part += g / __log2f((float)(1 + rr));
    }
    red[tid] = part;
    __syncthreads();
    for (int s = 128; s > 0; s >>= 1) {
        if (tid < s) red[tid] += red[tid + s];
        __syncthreads();
    }
    if (tid == 0) inv_maxdcg = 1.f / fmaxf(red[0], EPS);
    __syncthreads();
    const float invD = inv_maxdcg;

    float acc = 0.f;
    for (int k = tid; k < N; k += 256) {
        float S = 0.f;
        const float* p = ws + (size_t)r * QW * N + k;
#pragma unroll
        for (int q = 0; q < QW; ++q) S += p[q * N];
        float pos = 1.f + S;                    // self excluded in pairs_kernel
        float aD  = __log2f(1.f + pos);
        float g   = (fexp2(yt[k]) - 1.f) * invD;
        acc += g / aD;
    }
    red[tid] = acc;
    __syncthreads();
    for (int s = 128; s > 0; s >>= 1) {
        if (tid < s) red[tid] += red[tid + s];
        __syncthreads();
    }
    if (tid == 0) atomicAdd(out, red[0] * (1.f / BATCH));
}

extern "C" void kernel_launch(void* const* d_in, const int* in_sizes, int n_in,
                              void* d_out, int out_size, void* d_ws, size_t ws_size,
                              hipStream_t stream) {
    const float* y_pred = (const float*)d_in[0];
    const float* y_true = (const float*)d_in[1];
    float* out = (float*)d_out;
    float* ws  = (float*)d_ws;   // 32 rows x 16 slices x 2048 floats = 4 MB

    hipMemsetAsync(out, 0, sizeof(float), stream);   // graph-capturable memset node
    pairs_kernel<<<dim3(QW, BATCH), dim3(256), 0, stream>>>(y_pred, ws);
    finalize_kernel<<<dim3(BATCH), dim3(256), 0, stream>>>(y_true, ws, out);
}

// Round 3
// 97.565 us; speedup vs baseline: 4.3041x; 4.3041x over previous
//
#include <hip/hip_runtime.h>

#define EPS 5e-4f
#define LOG2E 1.4426950408889634f
#define BATCH 32
#define N 2048
#define QW 16   // pair-kernel blocks per row (u pairs tilerows u and 31-u)

__device__ __forceinline__ float fexp2(float x) { return __builtin_amdgcn_exp2f(x); }
__device__ __forceinline__ float frcp(float x)  { return __builtin_amdgcn_rcpf(x); }
// pull: dest lane m receives v from lane (idx_bytes[m] >> 2) & 63
__device__ __forceinline__ float bperm(int idx_bytes, float v) {
    return __int_as_float(__builtin_amdgcn_ds_bpermute(idx_bytes, __float_as_int(v)));
}

// S_k = sum_{l != k} sigmoid(p_l - p_k). Symmetry: one exp2+rcp serves BOTH
// directions of a pair; the mirrored credit is routed cross-lane with
// ds_bpermute into a register accumulator (NO atomics — R2's generic-pointer
// flat atomics were a 30x disaster). Each wave owns a private LDS S-copy.
// Tiles are stored doubled (128 floats) so the rotated b-read is
// ds_read_b32 [tilebase + lane*4] offset:jj*4 with zero per-iter VALU.
__global__ __launch_bounds__(256) void pairs_kernel(const float* __restrict__ y_pred,
                                                    float* __restrict__ ws) {
    const int r = blockIdx.y, u = blockIdx.x, v = 31 - u;
    const int tid = threadIdx.x, lane = tid & 63, wave = tid >> 6;
    __shared__ float pd[32 * 128];     // row * LOG2E, each 64-tile stored twice
    __shared__ float scol[4 * 2048];   // per-wave private S accumulators

    const float* yp = y_pred + r * N;
    for (int e = tid; e < N; e += 256) {
        float val = yp[e] * LOG2E;
        int t = e >> 6, m = e & 63;
        pd[t * 128 + m]      = val;
        pd[t * 128 + 64 + m] = val;
    }
    for (int c = tid; c < 4 * 2048; c += 256) scol[c] = 0.f;
    __syncthreads();

    const int lane4 = lane * 4;
    float* myS = &scol[wave * 2048];

    // Block u owns tilerows u and v=31-u of the upper triangle: 33 tile-tasks
    // (2 diagonal first for balance), round-robined over the 4 waves.
    for (int t = wave; t < 33; t += 4) {
        int i, j;
        if (t == 0)      { i = u; j = u; }
        else if (t == 1) { i = v; j = v; }
        else {
            int o = t - 2;
            if (o < 31 - u) { i = u; j = u + 1 + o; }
            else            { i = v; j = v + 1 + (o - (31 - u)); }
        }
        const float aL = pd[i * 128 + lane];
        const float* pb = &pd[j * 128 + lane];   // pb[jj] = p_b for b=(lane+jj)&63
        float accA = 0.f;    // row credits: sigma(p_b - p_a) for a = i*64+lane
        float accBn = 0.f;   // received rr's; column credit = cnt - accBn
        float colCnt;
        if (i != j) {
            colCnt = 64.f;
#pragma unroll
            for (int jj = 0; jj < 64; ++jj) {
                float rr = frcp(1.f + fexp2(aL - pb[jj]));  // sigma(p_b - p_a)
                accA += rr;
                accBn += bperm((lane4 - jj * 4) & 252, rr); // route to lane b
            }
        } else {
            // diagonal: jj=1..31 both credits (covers min-gaps 1..31 both
            // directions); jj=32 row-credit only (both directions appear
            // across lanes). No self-pair, no double count.
            colCnt = 31.f;
#pragma unroll
            for (int jj = 1; jj < 32; ++jj) {
                float rr = frcp(1.f + fexp2(aL - pb[jj]));
                accA += rr;
                accBn += bperm((lane4 - jj * 4) & 252, rr);
            }
            accA += frcp(1.f + fexp2(aL - pb[32]));
        }
        myS[i * 64 + lane] += accA;             // wave-private: plain RMW
        myS[j * 64 + lane] += colCnt - accBn;
    }
    __syncthreads();

    // fold the 4 wave-copies; every element of this block's ws slice written
    float* wsl = ws + ((size_t)r * QW + u) * N;
    for (int c = tid; c < N; c += 256)
        wsl[c] = scol[c] + scol[2048 + c] + scol[4096 + c] + scol[6144 + c];
}

// One block per row: maxDCG via 5-bin histogram (labels are ints 0..4, so the
// descending sort collapses to rank ranges), then the finalize sweep.
__global__ __launch_bounds__(256) void finalize_kernel(const float* __restrict__ y_true,
                                                       const float* __restrict__ ws,
                                                       float* __restrict__ out) {
    const int r   = blockIdx.x;
    const int tid = threadIdx.x;
    __shared__ int cnt[5];
    __shared__ float red[256];
    __shared__ float inv_maxdcg;
    if (tid < 5) cnt[tid] = 0;
    __syncthreads();

    const float* yt = y_true + r * N;
    int c1 = 0, c2 = 0, c3 = 0, c4 = 0;
    for (int i = tid; i < N; i += 256) {
        int vv = (int)yt[i];
        c1 += (vv == 1); c2 += (vv == 2); c3 += (vv == 3); c4 += (vv == 4);
    }
    atomicAdd(&cnt[1], c1);
    atomicAdd(&cnt[2], c2);
    atomicAdd(&cnt[3], c3);
    atomicAdd(&cnt[4], c4);
    __syncthreads();

    const int cum4 = cnt[4];
    const int cum3 = cum4 + cnt[3];
    const int cum2 = cum3 + cnt[2];
    const int cum1 = cum2 + cnt[1];

    float part = 0.f;
    for (int rr = tid + 1; rr <= N; rr += 256) {
        float g = (rr <= cum4) ? 15.f : (rr <= cum3) ? 7.f
                : (rr <= cum2) ? 3.f  : (rr <= cum1) ? 1.f : 0.f;
        if (g > 0.f) part += g / __log2f((float)(1 + rr));
    }
    red[tid] = part;
    __syncthreads();
    for (int s = 128; s > 0; s >>= 1) {
        if (tid < s) red[tid] += red[tid + s];
        __syncthreads();
    }
    if (tid == 0) inv_maxdcg = 1.f / fmaxf(red[0], EPS);
    __syncthreads();
    const float invD = inv_maxdcg;

    float acc = 0.f;
    for (int k = tid; k < N; k += 256) {
        float S = 0.f;
        const float* p = ws + (size_t)r * QW * N + k;
#pragma unroll
        for (int q = 0; q < QW; ++q) S += p[q * N];
        float pos = 1.f + S;                 // self term excluded in pairs_kernel
        float aD  = __log2f(1.f + pos);
        float g   = (fexp2(yt[k]) - 1.f) * invD;
        acc += g / aD;
    }
    red[tid] = acc;
    __syncthreads();
    for (int s = 128; s > 0; s >>= 1) {
        if (tid < s) red[tid] += red[tid + s];
        __syncthreads();
    }
    if (tid == 0) atomicAdd(out, red[0] * (1.f / BATCH));
}

extern "C" void kernel_launch(void* const* d_in, const int* in_sizes, int n_in,
                              void* d_out, int out_size, void* d_ws, size_t ws_size,
                              hipStream_t stream) {
    const float* y_pred = (const float*)d_in[0];
    const float* y_true = (const float*)d_in[1];
    float* out = (float*)d_out;
    float* ws  = (float*)d_ws;   // 32 rows x 16 slices x 2048 floats = 4 MB

    hipMemsetAsync(out, 0, sizeof(float), stream);
    pairs_kernel<<<dim3(QW, BATCH), dim3(256), 0, stream>>>(y_pred, ws);
    finalize_kernel<<<dim3(BATCH), dim3(256), 0, stream>>>(y_true, ws, out);
}